// Round 11
// baseline (518.156 us; speedup 1.0000x reference)
//
#include <hip/hip_runtime.h>
#include <hip/hip_bf16.h>

// ---------- helpers ----------
typedef __attribute__((ext_vector_type(8))) short bf16x8;
typedef __attribute__((ext_vector_type(4))) float f32x4;

static __device__ __forceinline__ short f2bf(float f) {
    unsigned u = __float_as_uint(f);
    unsigned r = (u + 0x7FFFu + ((u >> 16) & 1u)) >> 16;  // RNE
    return (short)(unsigned short)r;
}
static __device__ __forceinline__ float bf2f(short s) {
    return __uint_as_float(((unsigned)(unsigned short)s) << 16);
}

// async global->LDS, 16B per lane; LDS dest = wave-uniform base + lane*16 (m104)
static __device__ __forceinline__ void gload16(const void* g, void* l) {
    __builtin_amdgcn_global_load_lds((const __attribute__((address_space(1))) unsigned int*)g,
                                     (__attribute__((address_space(3))) unsigned int*)l, 16, 0, 0);
}

// raw workgroup barrier WITHOUT vmcnt(0) drain (unlike __syncthreads).
static __device__ __forceinline__ void wg_barrier() {
    asm volatile("" ::: "memory");
    __builtin_amdgcn_s_barrier();
    asm volatile("" ::: "memory");
}

// pack 8 fp32 -> bf16x8 (RNE, packed cvt where available)
static __device__ __forceinline__ bf16x8 cvt8(const f32x4 lo, const f32x4 hi) {
    __hip_bfloat162 p0 = __float22bfloat162_rn(make_float2(lo[0], lo[1]));
    __hip_bfloat162 p1 = __float22bfloat162_rn(make_float2(lo[2], lo[3]));
    __hip_bfloat162 p2 = __float22bfloat162_rn(make_float2(hi[0], hi[1]));
    __hip_bfloat162 p3 = __float22bfloat162_rn(make_float2(hi[2], hi[3]));
    short2 s0 = *(short2*)&p0, s1 = *(short2*)&p1, s2 = *(short2*)&p2, s3 = *(short2*)&p3;
    bf16x8 r = {s0.x, s0.y, s1.x, s1.y, s2.x, s2.y, s3.x, s3.y};
    return r;
}

// ---------- degree ----------
__global__ void deg_kernel(const int* __restrict__ src, const int* __restrict__ dst,
                           int* __restrict__ deg_out, int* __restrict__ deg_in, int E) {
    int e = blockIdx.x * blockDim.x + threadIdx.x;
    if (e < E) {
        atomicAdd(&deg_out[src[e]], 1);
        atomicAdd(&deg_in[dst[e]], 1);
    }
}

// ---------- 3-phase multi-block exclusive scan of deg_in -> offsets ----------
__global__ void scan_part1(const int* __restrict__ deg, int* __restrict__ bsum, int N) {
    __shared__ int red[256];
    int i = blockIdx.x * 256 + threadIdx.x;
    red[threadIdx.x] = (i < N) ? deg[i] : 0;
    __syncthreads();
    for (int off = 128; off > 0; off >>= 1) {
        if (threadIdx.x < off) red[threadIdx.x] += red[threadIdx.x + off];
        __syncthreads();
    }
    if (threadIdx.x == 0) bsum[blockIdx.x] = red[0];
}

__global__ void scan_part2(const int* __restrict__ bsum, int* __restrict__ bsum_ex, int NB,
                           int* __restrict__ offsets, int N, int E) {
    __shared__ int s[256];
    int t = threadIdx.x;
    int v = (t < NB) ? bsum[t] : 0;
    s[t] = v;
    __syncthreads();
    for (int off = 1; off < 256; off <<= 1) {
        int u = (t >= off) ? s[t - off] : 0;
        __syncthreads();
        s[t] += u;
        __syncthreads();
    }
    bsum_ex[t] = s[t] - v;  // exclusive
    if (t == 0) offsets[N] = E;
}

// scan_part3 + fused norm computation
__global__ void scan_part3(const int* __restrict__ deg_in, const int* __restrict__ deg_out,
                           const int* __restrict__ bsum_ex, int* __restrict__ offsets,
                           float* __restrict__ ns, float* __restrict__ nd, int N) {
    __shared__ int s[256];
    int t = threadIdx.x, i = blockIdx.x * 256 + t;
    int v = (i < N) ? deg_in[i] : 0;
    s[t] = v;
    __syncthreads();
    for (int off = 1; off < 256; off <<= 1) {
        int u = (t >= off) ? s[t - off] : 0;
        __syncthreads();
        s[t] += u;
        __syncthreads();
    }
    if (i < N) {
        offsets[i] = bsum_ex[blockIdx.x] + s[t] - v;
        ns[i] = rsqrtf((float)max(deg_out[i], 1));
        nd[i] = rsqrtf((float)max(v, 1));
    }
}

// ---------- scatter edges into CSR-by-dst buckets ----------
__global__ void scatter_kernel(const int* __restrict__ src, const int* __restrict__ dst,
                               const int* __restrict__ offsets, int* __restrict__ cursor,
                               int* __restrict__ bucket, int E) {
    int e = blockIdx.x * blockDim.x + threadIdx.x;
    if (e < E) {
        int d = dst[e];
        int p = atomicAdd(&cursor[d], 1);
        bucket[offsets[d] + p] = src[e];
    }
}

// ---------- W1 [K=1024][N=256] fp32 -> Wt [n][k] bf16 ----------
__global__ __launch_bounds__(1024) void transpose_w1(const float* __restrict__ W1,
                                                     short* __restrict__ Wt) {
    __shared__ short tile[32][33];
    int k0 = blockIdx.x * 32, n0 = blockIdx.y * 32;
    int tx = threadIdx.x & 31, ty = threadIdx.x >> 5;
    tile[ty][tx] = f2bf(W1[(size_t)(k0 + ty) * 256 + (n0 + tx)]);
    __syncthreads();
    Wt[(size_t)(n0 + ty) * 1024 + (k0 + tx)] = tile[tx][ty];
}

// ---------- GEMM1: hb = bf16((x @ W1) * norm_src[row]) ----------
// BYTES-IN-FLIGHT attack (Little's-law model of R4..R10: all variants kept
// ~1-1.5 KB/CU outstanding -> ~3.3 TB/s delivered -> neutral results).
// BK=64 (NKT=16) raises in-flight ~2.4x:
//  - A: direct global->VGPR, 16 x dwordx4 per lane per step in flight a
//    full step ahead (compiler tracks retirement exactly).
//  - B: LDS dbuf 2x32 KB, 8 gload_lds/wave/step, counted vmcnt(24):
//    retires B(t+1), keeps A(t+1):16 + B(t+2):8 in flight across barrier.
//  - 8-chunk XOR swizzle (chunk ^= n&7): ds_read <=2-way (free, m136).
// LDS = max(64, 67.6) KB -> 2 blocks/CU; acc in AGPRs keeps VGPR headroom.
#define BM 128
#define BN 256
#define BK 64
#define NKT 16   // 1024 / BK
#define CSTR 264 // C-staging row stride in shorts (528B, 16B-divisible)

union SMem {
    short B[2][BN * BK];  // 2 x 32 KB; row = 64 shorts = 8 chunks of 16B, stored chunk = logical ^ (n&7)
    short C[BM * CSTR];   // 67.6 KB epilogue staging
};

__global__ __launch_bounds__(256, 2) void gemm1_kernel(const float* __restrict__ x,
                                                       const short* __restrict__ Wt,
                                                       const float* __restrict__ norm_src,
                                                       short* __restrict__ hb, int M) {
    __shared__ __align__(16) SMem sm;
    __shared__ float ns_lds[BM];
    const int tid  = threadIdx.x;
    const int lane = tid & 63;
    const int wave = tid >> 6;
    const int quad = lane >> 4;
    const int mrow = lane & 15;
    const int wm = (wave >> 1) * 64;   // wave row offset (2 row-groups of 64)
    const int wn = (wave & 1) * 128;   // wave col offset (2 col-groups of 128)
    const int bm = blockIdx.x * BM;

    if (tid < BM) ns_lds[tid] = norm_src[min(bm + tid, M - 1)];

    f32x4 acc[4][8] = {};

    // per-lane A row pointers (const across k); clamped rows masked at C-write
    const float* aptr[4];
#pragma unroll
    for (int mi = 0; mi < 4; mi++) {
        int row = min(bm + wm + mi * 16 + mrow, M - 1);
        aptr[mi] = x + (size_t)row * 1024 + quad * 8;
    }

    // B staging lane roles: 8 lanes fill one 128B row; 8 rows per instr
    const int bR = lane >> 3;        // row within 8-row group (0..7)
    const int bC = (lane & 7) ^ bR;  // logical chunk (pre-swizzled source)

    auto stageB = [&](int buf, int k0) {  // 8 gload_lds / wave
#pragma unroll
        for (int i = 0; i < 8; i++) {
            int nbase = wave * 64 + i * 8;
            int n = nbase + bR;
            gload16(Wt + (size_t)n * 1024 + k0 + bC * 8, &sm.B[buf][nbase * 64]);
        }
    };

    f32x4 aLo0[4], aHi0[4], aLo1[4], aHi1[4];  // A(t) / A(t+1) f32 (reused)
    auto loadA = [&](int k) {
#pragma unroll
        for (int mi = 0; mi < 4; mi++) {
            aLo0[mi] = *(const f32x4*)(aptr[mi] + k);
            aHi0[mi] = *(const f32x4*)(aptr[mi] + k + 4);
            aLo1[mi] = *(const f32x4*)(aptr[mi] + k + 32);
            aHi1[mi] = *(const f32x4*)(aptr[mi] + k + 36);
        }
    };

    // prologue: queue [B(0):8, A(0):16, B(1):8]; vmcnt(24) retires B(0)
    stageB(0, 0);
    loadA(0);
    stageB(1, BK);
    asm volatile("s_waitcnt vmcnt(24)" ::: "memory");
    wg_barrier();  // B(0) published

    int cur = 0;
    for (int t = 0; t < NKT; t++) {
        // cvt A(t) both k-halves (compiler inserts the exact vmcnt to retire
        // the 16 A loads); then reuse the regs to issue A(t+1)
        bf16x8 af0[4], af1[4];
#pragma unroll
        for (int mi = 0; mi < 4; mi++) {
            af0[mi] = cvt8(aLo0[mi], aHi0[mi]);
            af1[mi] = cvt8(aLo1[mi], aHi1[mi]);
        }
        if (t + 1 < NKT) loadA((t + 1) * BK);

        // ---- compute tile t: k-half 0 then k-half 1 ----
        bf16x8 bfr[8];
#pragma unroll
        for (int ni = 0; ni < 8; ni++) {
            int n = wn + ni * 16 + mrow;
            bfr[ni] = *(const bf16x8*)&sm.B[cur][n * 64 + ((quad ^ (n & 7)) * 8)];
        }
#pragma unroll
        for (int mi = 0; mi < 4; mi++)
#pragma unroll
            for (int ni = 0; ni < 8; ni++)
                acc[mi][ni] = __builtin_amdgcn_mfma_f32_16x16x32_bf16(af0[mi], bfr[ni], acc[mi][ni], 0, 0, 0);
#pragma unroll
        for (int ni = 0; ni < 8; ni++) {
            int n = wn + ni * 16 + mrow;
            bfr[ni] = *(const bf16x8*)&sm.B[cur][n * 64 + (((4 + quad) ^ (n & 7)) * 8)];
        }
#pragma unroll
        for (int mi = 0; mi < 4; mi++)
#pragma unroll
            for (int ni = 0; ni < 8; ni++)
                acc[mi][ni] = __builtin_amdgcn_mfma_f32_16x16x32_bf16(af1[mi], bfr[ni], acc[mi][ni], 0, 0, 0);

        // all waves done reading B[cur] -> safe to restage into it
        wg_barrier();

        if (t + 2 < NKT) {
            stageB(cur, (t + 2) * BK);
            // in flight: [B(t+1):8, A(t+1):16, B(t+2):8] -> retire B(t+1)
            asm volatile("s_waitcnt vmcnt(24)" ::: "memory");
        } else if (t + 2 == NKT) {
            // in flight: [B(t+1):8, A(t+1):16] -> retire B(t+1)
            asm volatile("s_waitcnt vmcnt(16)" ::: "memory");
        } else {
            asm volatile("s_waitcnt vmcnt(0)" ::: "memory");  // drain tail
        }
        wg_barrier();  // B(t+1) published
        cur ^= 1;
    }

    // epilogue: acc -> C LDS (scaled, bf16), then coalesced 16B/lane stores.
    // Final vmcnt(0) + barrier guarantee the union B region is dead.
#pragma unroll
    for (int mi = 0; mi < 4; mi++) {
#pragma unroll
        for (int reg = 0; reg < 4; reg++) {
            int row = wm + mi * 16 + quad * 4 + reg;
            float nsv = ns_lds[row];
#pragma unroll
            for (int ni = 0; ni < 8; ni++) {
                int col = wn + ni * 16 + mrow;
                sm.C[row * CSTR + col] = f2bf(acc[mi][ni][reg] * nsv);
            }
        }
    }
    __syncthreads();
#pragma unroll
    for (int j = 0; j < 16; j++) {
        int row = wave * 2 + (lane >> 5) + j * 8;  // 8 rows/pass x 16 passes = 128
        int chunk = lane & 31;                     // 32 chunks x 8 shorts = 256 cols
        if (bm + row < M) {
            int4 v = *(const int4*)&sm.C[row * CSTR + chunk * 8];
            *(int4*)(hb + (size_t)(bm + row) * 256 + chunk * 8) = v;
        }
    }
}

// ---------- agg1 fused with layer-2 projection ----------
__global__ __launch_bounds__(256) void agg1_kernel(const short* __restrict__ hb,
                                                   const int* __restrict__ bucket,
                                                   const int* __restrict__ offsets,
                                                   const float* __restrict__ norm_dst,
                                                   const float* __restrict__ norm_src,
                                                   const float* __restrict__ b1,
                                                   const float* __restrict__ W2,
                                                   float* __restrict__ z, int N) {
    int wave = threadIdx.x >> 6;
    int lane = threadIdx.x & 63;
    int half = lane >> 5;       // which edge of the pair
    int col8 = lane & 31;       // 8-col group within 256
    int node = blockIdx.x * 4 + wave;
    if (node >= N) return;
    int beg = offsets[node], end = offsets[node + 1];
    float a[8] = {0.f, 0.f, 0.f, 0.f, 0.f, 0.f, 0.f, 0.f};
    int e = beg;
    for (; e + 16 <= end; e += 16) {  // 16 edges: 8 gathers of 16B in flight/lane
        bf16x8 v[8];
#pragma unroll
        for (int i = 0; i < 8; i++) {
            int s = bucket[e + 2 * i + half];
            v[i] = *(const bf16x8*)(hb + (size_t)s * 256 + col8 * 8);
        }
#pragma unroll
        for (int i = 0; i < 8; i++)
#pragma unroll
            for (int j = 0; j < 8; j++) a[j] += bf2f(v[i][j]);
    }
    for (; e + 8 <= end; e += 8) {
        bf16x8 v[4];
#pragma unroll
        for (int i = 0; i < 4; i++) {
            int s = bucket[e + 2 * i + half];
            v[i] = *(const bf16x8*)(hb + (size_t)s * 256 + col8 * 8);
        }
#pragma unroll
        for (int i = 0; i < 4; i++)
#pragma unroll
            for (int j = 0; j < 8; j++) a[j] += bf2f(v[i][j]);
    }
    for (; e + 2 <= end; e += 2) {
        int s0 = bucket[e + half];
        bf16x8 v0 = *(const bf16x8*)(hb + (size_t)s0 * 256 + col8 * 8);
#pragma unroll
        for (int j = 0; j < 8; j++) a[j] += bf2f(v0[j]);
    }
    if (e < end && half == 0) {
        int s0 = bucket[e];
        bf16x8 v0 = *(const bf16x8*)(hb + (size_t)s0 * 256 + col8 * 8);
#pragma unroll
        for (int j = 0; j < 8; j++) a[j] += bf2f(v0[j]);
    }
#pragma unroll
    for (int j = 0; j < 8; j++) a[j] += __shfl_xor(a[j], 32, 64);

    float nd = norm_dst[node];
    float4 b_lo = *(const float4*)(b1 + col8 * 8);
    float4 b_hi = *(const float4*)(b1 + col8 * 8 + 4);
    float4 w_lo = *(const float4*)(W2 + col8 * 8);
    float4 w_hi = *(const float4*)(W2 + col8 * 8 + 4);
    float p = 0.f;
    p += fmaxf(a[0] * nd + b_lo.x, 0.f) * w_lo.x;
    p += fmaxf(a[1] * nd + b_lo.y, 0.f) * w_lo.y;
    p += fmaxf(a[2] * nd + b_lo.z, 0.f) * w_lo.z;
    p += fmaxf(a[3] * nd + b_lo.w, 0.f) * w_lo.w;
    p += fmaxf(a[4] * nd + b_hi.x, 0.f) * w_hi.x;
    p += fmaxf(a[5] * nd + b_hi.y, 0.f) * w_hi.y;
    p += fmaxf(a[6] * nd + b_hi.z, 0.f) * w_hi.z;
    p += fmaxf(a[7] * nd + b_hi.w, 0.f) * w_hi.w;
#pragma unroll
    for (int off = 16; off > 0; off >>= 1) p += __shfl_xor(p, off, 64);
    if (lane == 0) z[node] = p * norm_src[node];
}

// ---------- agg2: out = relu(norm_dst * sum z[src] + b2) ----------
__global__ void agg2_kernel(const float* __restrict__ z, const int* __restrict__ bucket,
                            const int* __restrict__ offsets, const float* __restrict__ norm_dst,
                            const float* __restrict__ b2, float* __restrict__ out, int N) {
    int i = blockIdx.x * blockDim.x + threadIdx.x;
    if (i >= N) return;
    int beg = offsets[i], end = offsets[i + 1];
    float s = 0.f;
    for (int e = beg; e < end; e++) s += z[bucket[e]];
    out[i] = fmaxf(s * norm_dst[i] + b2[0], 0.f);
}

extern "C" void kernel_launch(void* const* d_in, const int* in_sizes, int n_in,
                              void* d_out, int out_size, void* d_ws, size_t ws_size,
                              hipStream_t stream) {
    const int D_HID = in_sizes[4];           // 256
    const int D_IN  = in_sizes[3] / D_HID;   // 1024
    const int N     = in_sizes[0] / D_IN;    // 50000
    const int E     = in_sizes[1];           // 800000

    const float* x   = (const float*)d_in[0];
    const int*   src = (const int*)d_in[1];
    const int*   dst = (const int*)d_in[2];
    const float* W1  = (const float*)d_in[3];
    const float* b1  = (const float*)d_in[4];
    const float* W2  = (const float*)d_in[5];
    const float* b2  = (const float*)d_in[6];
    float* out = (float*)d_out;

    char* p = (char*)d_ws;
    auto alloc = [&](size_t bytes) {
        void* r = (void*)p;
        p += (bytes + 255) & ~(size_t)255;
        return r;
    };
    int*   deg_out  = (int*)alloc((size_t)N * 4);
    int*   deg_in   = (int*)alloc((size_t)N * 4);
    int*   cursor   = (int*)alloc((size_t)N * 4);
    float* norm_src = (float*)alloc((size_t)N * 4);
    float* norm_dst = (float*)alloc((size_t)N * 4);
    int*   offsets  = (int*)alloc((size_t)(N + 1) * 4);
    int*   bucket   = (int*)alloc((size_t)E * 4);
    short* Wt       = (short*)alloc((size_t)D_IN * D_HID * 2);
    short* hb       = (short*)alloc((size_t)N * D_HID * 2);
    float* z        = (float*)alloc((size_t)N * 4);
    int*   bsum     = (int*)alloc(256 * 4);
    int*   bsum_ex  = (int*)alloc(256 * 4);

    const int NB = (N + 255) / 256;  // 196 scan blocks

    // deg_out, deg_in, cursor are contiguous (256B-aligned) -> one memset
    size_t degpad = ((size_t)N * 4 + 255) & ~(size_t)255;
    hipMemsetAsync(deg_out, 0, degpad * 2 + (size_t)N * 4, stream);

    deg_kernel<<<(E + 255) / 256, 256, 0, stream>>>(src, dst, deg_out, deg_in, E);
    scan_part1<<<NB, 256, 0, stream>>>(deg_in, bsum, N);
    scan_part2<<<1, 256, 0, stream>>>(bsum, bsum_ex, NB, offsets, N, E);
    scan_part3<<<NB, 256, 0, stream>>>(deg_in, deg_out, bsum_ex, offsets, norm_src, norm_dst, N);
    scatter_kernel<<<(E + 255) / 256, 256, 0, stream>>>(src, dst, offsets, cursor, bucket, E);
    transpose_w1<<<dim3(D_IN / 32, D_HID / 32), 1024, 0, stream>>>(W1, Wt);
    gemm1_kernel<<<dim3((N + BM - 1) / BM), 256, 0, stream>>>(x, Wt, norm_src, hb, N);
    agg1_kernel<<<(N + 3) / 4, 256, 0, stream>>>(hb, bucket, offsets, norm_dst, norm_src, b1, W2, z, N);
    agg2_kernel<<<(N + 255) / 256, 256, 0, stream>>>(z, bucket, offsets, norm_dst, b2, out, N);
}

// Round 12
// 468.051 us; speedup vs baseline: 1.1070x; 1.1070x over previous
//
#include <hip/hip_runtime.h>
#include <hip/hip_bf16.h>

// ---------- helpers ----------
typedef __attribute__((ext_vector_type(8))) short bf16x8;
typedef __attribute__((ext_vector_type(4))) float f32x4;

static __device__ __forceinline__ short f2bf(float f) {
    unsigned u = __float_as_uint(f);
    unsigned r = (u + 0x7FFFu + ((u >> 16) & 1u)) >> 16;  // RNE
    return (short)(unsigned short)r;
}
static __device__ __forceinline__ float bf2f(short s) {
    return __uint_as_float(((unsigned)(unsigned short)s) << 16);
}

// async global->LDS, 16B per lane; LDS dest = wave-uniform base + lane*16 (m104)
static __device__ __forceinline__ void gload16(const void* g, void* l) {
    __builtin_amdgcn_global_load_lds((const __attribute__((address_space(1))) unsigned int*)g,
                                     (__attribute__((address_space(3))) unsigned int*)l, 16, 0, 0);
}

// raw workgroup barrier WITHOUT vmcnt(0) drain (unlike __syncthreads).
static __device__ __forceinline__ void wg_barrier() {
    asm volatile("" ::: "memory");
    __builtin_amdgcn_s_barrier();
    asm volatile("" ::: "memory");
}

// pack 8 fp32 -> bf16x8 (RNE, packed cvt where available)
static __device__ __forceinline__ bf16x8 cvt8(const f32x4 lo, const f32x4 hi) {
    __hip_bfloat162 p0 = __float22bfloat162_rn(make_float2(lo[0], lo[1]));
    __hip_bfloat162 p1 = __float22bfloat162_rn(make_float2(lo[2], lo[3]));
    __hip_bfloat162 p2 = __float22bfloat162_rn(make_float2(hi[0], hi[1]));
    __hip_bfloat162 p3 = __float22bfloat162_rn(make_float2(hi[2], hi[3]));
    short2 s0 = *(short2*)&p0, s1 = *(short2*)&p1, s2 = *(short2*)&p2, s3 = *(short2*)&p3;
    bf16x8 r = {s0.x, s0.y, s1.x, s1.y, s2.x, s2.y, s3.x, s3.y};
    return r;
}

// ---------- fused degree + W1 transpose ----------
// blocks [0,256): transpose W1 [1024][256] fp32 -> Wt [256][1024] bf16
// blocks [256, 256+ceil(E/256)): degree atomics; atomicAdd's RETURN VALUE
// on deg_in is the edge's rank within its dst bucket -> scatter later
// needs NO atomics (cursor array eliminated).
__global__ __launch_bounds__(256) void deg_tr_kernel(const float* __restrict__ W1,
                                                     short* __restrict__ Wt,
                                                     const int* __restrict__ src,
                                                     const int* __restrict__ dst,
                                                     int* __restrict__ deg_out,
                                                     int* __restrict__ deg_in,
                                                     int* __restrict__ rank, int E) {
    int bid = blockIdx.x, tid = threadIdx.x;
    if (bid < 256) {
        __shared__ short tile[32][33];
        int k0 = (bid & 31) * 32, n0 = (bid >> 5) * 32;
        int tx = tid & 31, ty = tid >> 5;  // 32 cols x 8 rows/pass
#pragma unroll
        for (int p = 0; p < 4; p++) {
            int r = p * 8 + ty;
            tile[r][tx] = f2bf(W1[(size_t)(k0 + r) * 256 + (n0 + tx)]);
        }
        __syncthreads();
#pragma unroll
        for (int p = 0; p < 4; p++) {
            int r = p * 8 + ty;
            Wt[(size_t)(n0 + r) * 1024 + (k0 + tx)] = tile[tx][r];
        }
    } else {
        int e = (bid - 256) * 256 + tid;
        if (e < E) {
            atomicAdd(&deg_out[src[e]], 1);
            rank[e] = atomicAdd(&deg_in[dst[e]], 1);
        }
    }
}

// ---------- 3-phase multi-block exclusive scan of deg_in -> offsets ----------
__global__ void scan_part1(const int* __restrict__ deg, int* __restrict__ bsum, int N) {
    __shared__ int red[256];
    int i = blockIdx.x * 256 + threadIdx.x;
    red[threadIdx.x] = (i < N) ? deg[i] : 0;
    __syncthreads();
    for (int off = 128; off > 0; off >>= 1) {
        if (threadIdx.x < off) red[threadIdx.x] += red[threadIdx.x + off];
        __syncthreads();
    }
    if (threadIdx.x == 0) bsum[blockIdx.x] = red[0];
}

__global__ void scan_part2(const int* __restrict__ bsum, int* __restrict__ bsum_ex, int NB,
                           int* __restrict__ offsets, int N, int E) {
    __shared__ int s[256];
    int t = threadIdx.x;
    int v = (t < NB) ? bsum[t] : 0;
    s[t] = v;
    __syncthreads();
    for (int off = 1; off < 256; off <<= 1) {
        int u = (t >= off) ? s[t - off] : 0;
        __syncthreads();
        s[t] += u;
        __syncthreads();
    }
    bsum_ex[t] = s[t] - v;  // exclusive
    if (t == 0) offsets[N] = E;
}

// scan_part3 + fused norm computation
__global__ void scan_part3(const int* __restrict__ deg_in, const int* __restrict__ deg_out,
                           const int* __restrict__ bsum_ex, int* __restrict__ offsets,
                           float* __restrict__ ns, float* __restrict__ nd, int N) {
    __shared__ int s[256];
    int t = threadIdx.x, i = blockIdx.x * 256 + t;
    int v = (i < N) ? deg_in[i] : 0;
    s[t] = v;
    __syncthreads();
    for (int off = 1; off < 256; off <<= 1) {
        int u = (t >= off) ? s[t - off] : 0;
        __syncthreads();
        s[t] += u;
        __syncthreads();
    }
    if (i < N) {
        offsets[i] = bsum_ex[blockIdx.x] + s[t] - v;
        ns[i] = rsqrtf((float)max(deg_out[i], 1));
        nd[i] = rsqrtf((float)max(v, 1));
    }
}

// ---------- GEMM1 fused with atomic-free scatter ----------
// Blocks [0, GB): EXACT R4 champion GEMM (best measured; 72 VGPR,
//   all-LDS dbuf staging, raw s_barrier + counted vmcnt(8)).
// Blocks [GB, GB+SCB): scatter bucket[offsets[dst]+rank] = src.
// The two roles are independent (scatter writes bucket; GEMM writes hb) and
// both depend only on scan3/transpose -> scatter's ~40-60us of random-access
// latency hides under the GEMM's memory stalls instead of serializing.
#define BM 128
#define BN 256
#define BK 32
#define NKT 32   // 1024 / BK
#define CSTR 264 // C-staging row stride in shorts (528B, 16B-divisible)
#define SCB 782  // scatter blocks

union SMem {
    struct {
        float A[2][BM * BK];  // 2 x 16 KB; row = 32 floats = 8 chunks of 16B, stored chunk = logical ^ (r&7)
        short B[2][BN * BK];  // 2 x 16 KB; row = 32 shorts = 4 chunks of 16B, stored chunk = logical ^ ((n>>1)&3)
    } s;
    short C[BM * CSTR];       // 67.6 KB epilogue staging
};

__global__ __launch_bounds__(256, 2) void gemm_scatter_kernel(
    const float* __restrict__ x, const short* __restrict__ Wt,
    const float* __restrict__ norm_src, short* __restrict__ hb, int M,
    const int* __restrict__ src, const int* __restrict__ dst,
    const int* __restrict__ offsets, const int* __restrict__ rank,
    int* __restrict__ bucket, int E, int GB) {
    __shared__ __align__(16) SMem sm;
    __shared__ float ns_lds[BM];

    if ((int)blockIdx.x >= GB) {
        // ---------------- scatter role ----------------
        int base = ((int)blockIdx.x - GB) * 256 + threadIdx.x;
        for (int e = base; e < E; e += SCB * 256) {
            bucket[offsets[dst[e]] + rank[e]] = src[e];
        }
        return;
    }

    // ---------------- GEMM role (R4 exact) ----------------
    const int tid  = threadIdx.x;
    const int lane = tid & 63;
    const int wave = tid >> 6;
    const int quad = lane >> 4;
    const int mrow = lane & 15;
    const int wm = (wave >> 1) * 64;   // wave row offset (2 row-groups of 64)
    const int wn = (wave & 1) * 128;   // wave col offset (2 col-groups of 128)
    const int bm = blockIdx.x * BM;

    if (tid < BM) ns_lds[tid] = norm_src[min(bm + tid, M - 1)];

    f32x4 acc[4][8] = {};

    // staging lane roles (constant across k)
    const int aL_r = lane >> 3;                       // row within 8-row group
    const int aL_c = (lane & 7) ^ (aL_r & 7);         // logical chunk (swizzle)
    const int bL_r = lane >> 2;                       // row within 16-row group
    const int bL_c = (lane & 3) ^ ((lane >> 3) & 3);  // logical chunk (swizzle)

    // 8 loads/stage/wave, UNCONDITIONAL (row clamped -> uniform vmcnt)
    auto stageAB = [&](int buf, int k0) {
#pragma unroll
        for (int i = 0; i < 4; i++) {
            int rowbase = wave * 32 + i * 8;
            int r = min(bm + rowbase + aL_r, M - 1);
            gload16(x + (size_t)r * 1024 + k0 + aL_c * 4, &sm.s.A[buf][rowbase * 32]);
        }
#pragma unroll
        for (int i = 0; i < 4; i++) {
            int nbase = wave * 64 + i * 16;
            int n = nbase + bL_r;
            gload16(Wt + (size_t)n * 1024 + k0 + bL_c * 8, &sm.s.B[buf][nbase * 32]);
        }
    };

    // prologue: fill both buffers; wait only for tile 0 (8 newest stay in flight)
    stageAB(0, 0);
    stageAB(1, BK);
    asm volatile("s_waitcnt vmcnt(8)" ::: "memory");
    wg_barrier();

    int cur = 0;
    for (int t = 0; t < NKT; t++) {
        bf16x8 af[4], bfr[8];
#pragma unroll
        for (int mi = 0; mi < 4; mi++) {
            int row = wm + mi * 16 + mrow;
            f32x4 lo = *(const f32x4*)&sm.s.A[cur][row * 32 + (((quad * 2 + 0) ^ (mrow & 7)) * 4)];
            f32x4 hi = *(const f32x4*)&sm.s.A[cur][row * 32 + (((quad * 2 + 1) ^ (mrow & 7)) * 4)];
            af[mi] = cvt8(lo, hi);
        }
#pragma unroll
        for (int ni = 0; ni < 8; ni++) {
            int n = wn + ni * 16 + mrow;
            bfr[ni] = *(const bf16x8*)&sm.s.B[cur][n * 32 + ((quad ^ ((mrow >> 1) & 3)) * 8)];
        }
#pragma unroll
        for (int mi = 0; mi < 4; mi++)
#pragma unroll
            for (int ni = 0; ni < 8; ni++)
                acc[mi][ni] = __builtin_amdgcn_mfma_f32_16x16x32_bf16(af[mi], bfr[ni], acc[mi][ni], 0, 0, 0);

        wg_barrier();  // all waves done reading buf[cur]

        if (t + 2 < NKT) {
            stageAB(cur, (t + 2) * BK);                      // 8 new loads
            asm volatile("s_waitcnt vmcnt(8)" ::: "memory"); // oldest 8 = tile t+1 landed
        } else {
            asm volatile("s_waitcnt vmcnt(0)" ::: "memory"); // drain remaining
        }
        wg_barrier();  // buf[cur^1] fully resident
        cur ^= 1;
    }

    // epilogue: acc -> C LDS (scaled, bf16), then coalesced 16B/lane stores.
#pragma unroll
    for (int mi = 0; mi < 4; mi++) {
#pragma unroll
        for (int reg = 0; reg < 4; reg++) {
            int row = wm + mi * 16 + quad * 4 + reg;
            float nsv = ns_lds[row];
#pragma unroll
            for (int ni = 0; ni < 8; ni++) {
                int col = wn + ni * 16 + mrow;
                sm.C[row * CSTR + col] = f2bf(acc[mi][ni][reg] * nsv);
            }
        }
    }
    __syncthreads();
#pragma unroll
    for (int j = 0; j < 16; j++) {
        int row = wave * 2 + (lane >> 5) + j * 8;  // 8 rows/pass x 16 passes = 128
        int chunk = lane & 31;                     // 32 chunks x 8 shorts = 256 cols
        if (bm + row < M) {
            int4 v = *(const int4*)&sm.C[row * CSTR + chunk * 8];
            *(int4*)(hb + (size_t)(bm + row) * 256 + chunk * 8) = v;
        }
    }
}

// ---------- agg1 fused with layer-2 projection ----------
__global__ __launch_bounds__(256) void agg1_kernel(const short* __restrict__ hb,
                                                   const int* __restrict__ bucket,
                                                   const int* __restrict__ offsets,
                                                   const float* __restrict__ norm_dst,
                                                   const float* __restrict__ norm_src,
                                                   const float* __restrict__ b1,
                                                   const float* __restrict__ W2,
                                                   float* __restrict__ z, int N) {
    int wave = threadIdx.x >> 6;
    int lane = threadIdx.x & 63;
    int half = lane >> 5;       // which edge of the pair
    int col8 = lane & 31;       // 8-col group within 256
    int node = blockIdx.x * 4 + wave;
    if (node >= N) return;
    int beg = offsets[node], end = offsets[node + 1];
    float a[8] = {0.f, 0.f, 0.f, 0.f, 0.f, 0.f, 0.f, 0.f};
    int e = beg;
    for (; e + 16 <= end; e += 16) {  // 16 edges: 8 gathers of 16B in flight/lane
        bf16x8 v[8];
#pragma unroll
        for (int i = 0; i < 8; i++) {
            int s = bucket[e + 2 * i + half];
            v[i] = *(const bf16x8*)(hb + (size_t)s * 256 + col8 * 8);
        }
#pragma unroll
        for (int i = 0; i < 8; i++)
#pragma unroll
            for (int j = 0; j < 8; j++) a[j] += bf2f(v[i][j]);
    }
    for (; e + 8 <= end; e += 8) {
        bf16x8 v[4];
#pragma unroll
        for (int i = 0; i < 4; i++) {
            int s = bucket[e + 2 * i + half];
            v[i] = *(const bf16x8*)(hb + (size_t)s * 256 + col8 * 8);
        }
#pragma unroll
        for (int i = 0; i < 4; i++)
#pragma unroll
            for (int j = 0; j < 8; j++) a[j] += bf2f(v[i][j]);
    }
    for (; e + 2 <= end; e += 2) {
        int s0 = bucket[e + half];
        bf16x8 v0 = *(const bf16x8*)(hb + (size_t)s0 * 256 + col8 * 8);
#pragma unroll
        for (int j = 0; j < 8; j++) a[j] += bf2f(v0[j]);
    }
    if (e < end && half == 0) {
        int s0 = bucket[e];
        bf16x8 v0 = *(const bf16x8*)(hb + (size_t)s0 * 256 + col8 * 8);
#pragma unroll
        for (int j = 0; j < 8; j++) a[j] += bf2f(v0[j]);
    }
#pragma unroll
    for (int j = 0; j < 8; j++) a[j] += __shfl_xor(a[j], 32, 64);

    float nd = norm_dst[node];
    float4 b_lo = *(const float4*)(b1 + col8 * 8);
    float4 b_hi = *(const float4*)(b1 + col8 * 8 + 4);
    float4 w_lo = *(const float4*)(W2 + col8 * 8);
    float4 w_hi = *(const float4*)(W2 + col8 * 8 + 4);
    float p = 0.f;
    p += fmaxf(a[0] * nd + b_lo.x, 0.f) * w_lo.x;
    p += fmaxf(a[1] * nd + b_lo.y, 0.f) * w_lo.y;
    p += fmaxf(a[2] * nd + b_lo.z, 0.f) * w_lo.z;
    p += fmaxf(a[3] * nd + b_lo.w, 0.f) * w_lo.w;
    p += fmaxf(a[4] * nd + b_hi.x, 0.f) * w_hi.x;
    p += fmaxf(a[5] * nd + b_hi.y, 0.f) * w_hi.y;
    p += fmaxf(a[6] * nd + b_hi.z, 0.f) * w_hi.z;
    p += fmaxf(a[7] * nd + b_hi.w, 0.f) * w_hi.w;
#pragma unroll
    for (int off = 16; off > 0; off >>= 1) p += __shfl_xor(p, off, 64);
    if (lane == 0) z[node] = p * norm_src[node];
}

// ---------- agg2: out = relu(norm_dst * sum z[src] + b2) ----------
__global__ void agg2_kernel(const float* __restrict__ z, const int* __restrict__ bucket,
                            const int* __restrict__ offsets, const float* __restrict__ norm_dst,
                            const float* __restrict__ b2, float* __restrict__ out, int N) {
    int i = blockIdx.x * blockDim.x + threadIdx.x;
    if (i >= N) return;
    int beg = offsets[i], end = offsets[i + 1];
    float s = 0.f;
    for (int e = beg; e < end; e++) s += z[bucket[e]];
    out[i] = fmaxf(s * norm_dst[i] + b2[0], 0.f);
}

extern "C" void kernel_launch(void* const* d_in, const int* in_sizes, int n_in,
                              void* d_out, int out_size, void* d_ws, size_t ws_size,
                              hipStream_t stream) {
    const int D_HID = in_sizes[4];           // 256
    const int D_IN  = in_sizes[3] / D_HID;   // 1024
    const int N     = in_sizes[0] / D_IN;    // 50000
    const int E     = in_sizes[1];           // 800000

    const float* x   = (const float*)d_in[0];
    const int*   src = (const int*)d_in[1];
    const int*   dst = (const int*)d_in[2];
    const float* W1  = (const float*)d_in[3];
    const float* b1  = (const float*)d_in[4];
    const float* W2  = (const float*)d_in[5];
    const float* b2  = (const float*)d_in[6];
    float* out = (float*)d_out;

    char* p = (char*)d_ws;
    auto alloc = [&](size_t bytes) {
        void* r = (void*)p;
        p += (bytes + 255) & ~(size_t)255;
        return r;
    };
    int*   deg_out  = (int*)alloc((size_t)N * 4);
    int*   deg_in   = (int*)alloc((size_t)N * 4);
    float* norm_src = (float*)alloc((size_t)N * 4);
    float* norm_dst = (float*)alloc((size_t)N * 4);
    int*   offsets  = (int*)alloc((size_t)(N + 1) * 4);
    int*   rank     = (int*)alloc((size_t)E * 4);
    int*   bucket   = (int*)alloc((size_t)E * 4);
    short* Wt       = (short*)alloc((size_t)D_IN * D_HID * 2);
    short* hb       = (short*)alloc((size_t)N * D_HID * 2);
    float* z        = (float*)alloc((size_t)N * 4);
    int*   bsum     = (int*)alloc(256 * 4);
    int*   bsum_ex  = (int*)alloc(256 * 4);

    const int NB = (N + 255) / 256;  // 196 scan blocks
    const int GB = (N + BM - 1) / BM;  // 391 gemm blocks

    // deg_out, deg_in contiguous (256B-aligned) -> one memset (cursor eliminated)
    size_t degpad = ((size_t)N * 4 + 255) & ~(size_t)255;
    hipMemsetAsync(deg_out, 0, degpad + (size_t)N * 4, stream);

    deg_tr_kernel<<<256 + (E + 255) / 256, 256, 0, stream>>>(W1, Wt, src, dst, deg_out, deg_in, rank, E);
    scan_part1<<<NB, 256, 0, stream>>>(deg_in, bsum, N);
    scan_part2<<<1, 256, 0, stream>>>(bsum, bsum_ex, NB, offsets, N, E);
    scan_part3<<<NB, 256, 0, stream>>>(deg_in, deg_out, bsum_ex, offsets, norm_src, norm_dst, N);
    gemm_scatter_kernel<<<GB + SCB, 256, 0, stream>>>(x, Wt, norm_src, hb, N,
                                                      src, dst, offsets, rank, bucket, E, GB);
    agg1_kernel<<<(N + 3) / 4, 256, 0, stream>>>(hb, bucket, offsets, norm_dst, norm_src, b1, W2, z, N);
    agg2_kernel<<<(N + 255) / 256, 256, 0, stream>>>(z, bucket, offsets, norm_dst, b2, out, N);
}

// Round 13
// 461.283 us; speedup vs baseline: 1.1233x; 1.0147x over previous
//
#include <hip/hip_runtime.h>
#include <hip/hip_bf16.h>

// ---------- helpers ----------
typedef __attribute__((ext_vector_type(8))) short bf16x8;
typedef __attribute__((ext_vector_type(4))) float f32x4;

static __device__ __forceinline__ short f2bf(float f) {
    unsigned u = __float_as_uint(f);
    unsigned r = (u + 0x7FFFu + ((u >> 16) & 1u)) >> 16;  // RNE
    return (short)(unsigned short)r;
}
static __device__ __forceinline__ float bf2f(short s) {
    return __uint_as_float(((unsigned)(unsigned short)s) << 16);
}

// async global->LDS, 16B per lane; LDS dest = wave-uniform base + lane*16 (m104)
static __device__ __forceinline__ void gload16(const void* g, void* l) {
    __builtin_amdgcn_global_load_lds((const __attribute__((address_space(1))) unsigned int*)g,
                                     (__attribute__((address_space(3))) unsigned int*)l, 16, 0, 0);
}

// raw workgroup barrier WITHOUT vmcnt(0) drain (unlike __syncthreads).
static __device__ __forceinline__ void wg_barrier() {
    asm volatile("" ::: "memory");
    __builtin_amdgcn_s_barrier();
    asm volatile("" ::: "memory");
}

// pack 8 fp32 -> bf16x8 (RNE, packed cvt where available)
static __device__ __forceinline__ bf16x8 cvt8(const f32x4 lo, const f32x4 hi) {
    __hip_bfloat162 p0 = __float22bfloat162_rn(make_float2(lo[0], lo[1]));
    __hip_bfloat162 p1 = __float22bfloat162_rn(make_float2(lo[2], lo[3]));
    __hip_bfloat162 p2 = __float22bfloat162_rn(make_float2(hi[0], hi[1]));
    __hip_bfloat162 p3 = __float22bfloat162_rn(make_float2(hi[2], hi[3]));
    short2 s0 = *(short2*)&p0, s1 = *(short2*)&p1, s2 = *(short2*)&p2, s3 = *(short2*)&p3;
    bf16x8 r = {s0.x, s0.y, s1.x, s1.y, s2.x, s2.y, s3.x, s3.y};
    return r;
}

// ---------- fused degree + W1 transpose ----------
// blocks [0,256): transpose W1 [1024][256] fp32 -> Wt [256][1024] bf16
// blocks [256, ...): degree atomics; atomicAdd's RETURN VALUE on deg_in is
// the edge's rank within its dst bucket -> scatter needs NO atomics.
__global__ __launch_bounds__(256) void deg_tr_kernel(const float* __restrict__ W1,
                                                     short* __restrict__ Wt,
                                                     const int* __restrict__ src,
                                                     const int* __restrict__ dst,
                                                     int* __restrict__ deg_out,
                                                     int* __restrict__ deg_in,
                                                     int* __restrict__ rank, int E) {
    int bid = blockIdx.x, tid = threadIdx.x;
    if (bid < 256) {
        __shared__ short tile[32][33];
        int k0 = (bid & 31) * 32, n0 = (bid >> 5) * 32;
        int tx = tid & 31, ty = tid >> 5;  // 32 cols x 8 rows/pass
#pragma unroll
        for (int p = 0; p < 4; p++) {
            int r = p * 8 + ty;
            tile[r][tx] = f2bf(W1[(size_t)(k0 + r) * 256 + (n0 + tx)]);
        }
        __syncthreads();
#pragma unroll
        for (int p = 0; p < 4; p++) {
            int r = p * 8 + ty;
            Wt[(size_t)(n0 + r) * 1024 + (k0 + tx)] = tile[tx][r];
        }
    } else {
        int e = (bid - 256) * 256 + tid;
        if (e < E) {
            atomicAdd(&deg_out[src[e]], 1);
            rank[e] = atomicAdd(&deg_in[dst[e]], 1);
        }
    }
}

// ---------- single-pass decoupled-lookback scan + norm (replaces 3 kernels) ----------
// All 196 blocks co-resident (<< 2048-block capacity) -> predecessors always
// make progress, no deadlock. Status word: 0=invalid, 0x4000_0000|aggregate,
// 0x8000_0000|inclusive_prefix (values < 2^20 << 30-bit payload). Payload is
// inside the single atomic word -> device-scope atomics alone give coherence
// across XCDs (G16); no separate fence needed.
__global__ __launch_bounds__(256) void scan_fused(const int* __restrict__ deg_in,
                                                  const int* __restrict__ deg_out,
                                                  unsigned* __restrict__ status,
                                                  int* __restrict__ offsets,
                                                  float* __restrict__ ns,
                                                  float* __restrict__ nd, int N, int E) {
    __shared__ int s[256];
    __shared__ int sprefix;
    int b = blockIdx.x, t = threadIdx.x;
    int i = b * 256 + t;
    int v = (i < N) ? deg_in[i] : 0;
    s[t] = v;
    __syncthreads();
    for (int off = 1; off < 256; off <<= 1) {  // inclusive scan
        int u = (t >= off) ? s[t - off] : 0;
        __syncthreads();
        s[t] += u;
        __syncthreads();
    }
    int total = s[255];
    if (t == 0) {
        if (b == 0) {
            atomicExch(&status[0], 0x80000000u | (unsigned)total);
            sprefix = 0;
        } else {
            atomicExch(&status[b], 0x40000000u | (unsigned)total);  // publish A first
            int prefix = 0, j = b - 1;
            while (true) {
                unsigned sj = atomicOr(&status[j], 0u);  // device-scope read
                if (sj & 0x80000000u) { prefix += (int)(sj & 0x3FFFFFFFu); break; }
                if (sj & 0x40000000u) { prefix += (int)(sj & 0x3FFFFFFFu); j--; }
                // else: spin until predecessor publishes
            }
            atomicExch(&status[b], 0x80000000u | (unsigned)(prefix + total));
            sprefix = prefix;
        }
    }
    __syncthreads();
    int bp = sprefix;
    if (i < N) {
        offsets[i] = bp + s[t] - v;  // exclusive
        ns[i] = rsqrtf((float)max(deg_out[i], 1));
        nd[i] = rsqrtf((float)max(v, 1));
    }
    if (i == 0) offsets[N] = E;
}

// ---------- GEMM1 fused with atomic-free scatter ----------
// Blocks [0, GB): EXACT R4 champion GEMM (best measured; all-LDS dbuf
//   staging, raw s_barrier + counted vmcnt(8)).
// Blocks [GB, GB+SCB): scatter bucket[offsets[dst]+rank] = src -- hides
//   under the GEMM's memory stalls instead of serializing (R12: -21 us).
#define BM 128
#define BN 256
#define BK 32
#define NKT 32   // 1024 / BK
#define CSTR 264 // C-staging row stride in shorts (528B, 16B-divisible)
#define SCB 782  // scatter blocks

union SMem {
    struct {
        float A[2][BM * BK];  // 2 x 16 KB; row = 32 floats = 8 chunks of 16B, stored chunk = logical ^ (r&7)
        short B[2][BN * BK];  // 2 x 16 KB; row = 32 shorts = 4 chunks of 16B, stored chunk = logical ^ ((n>>1)&3)
    } s;
    short C[BM * CSTR];       // 67.6 KB epilogue staging
};

__global__ __launch_bounds__(256, 2) void gemm_scatter_kernel(
    const float* __restrict__ x, const short* __restrict__ Wt,
    const float* __restrict__ norm_src, short* __restrict__ hb, int M,
    const int* __restrict__ src, const int* __restrict__ dst,
    const int* __restrict__ offsets, const int* __restrict__ rank,
    int* __restrict__ bucket, int E, int GB) {
    __shared__ __align__(16) SMem sm;
    __shared__ float ns_lds[BM];

    if ((int)blockIdx.x >= GB) {
        // ---------------- scatter role ----------------
        int base = ((int)blockIdx.x - GB) * 256 + threadIdx.x;
        for (int e = base; e < E; e += SCB * 256) {
            bucket[offsets[dst[e]] + rank[e]] = src[e];
        }
        return;
    }

    // ---------------- GEMM role (R4 exact) ----------------
    const int tid  = threadIdx.x;
    const int lane = tid & 63;
    const int wave = tid >> 6;
    const int quad = lane >> 4;
    const int mrow = lane & 15;
    const int wm = (wave >> 1) * 64;   // wave row offset (2 row-groups of 64)
    const int wn = (wave & 1) * 128;   // wave col offset (2 col-groups of 128)
    const int bm = blockIdx.x * BM;

    if (tid < BM) ns_lds[tid] = norm_src[min(bm + tid, M - 1)];

    f32x4 acc[4][8] = {};

    // staging lane roles (constant across k)
    const int aL_r = lane >> 3;                       // row within 8-row group
    const int aL_c = (lane & 7) ^ (aL_r & 7);         // logical chunk (swizzle)
    const int bL_r = lane >> 2;                       // row within 16-row group
    const int bL_c = (lane & 3) ^ ((lane >> 3) & 3);  // logical chunk (swizzle)

    // 8 loads/stage/wave, UNCONDITIONAL (row clamped -> uniform vmcnt)
    auto stageAB = [&](int buf, int k0) {
#pragma unroll
        for (int i = 0; i < 4; i++) {
            int rowbase = wave * 32 + i * 8;
            int r = min(bm + rowbase + aL_r, M - 1);
            gload16(x + (size_t)r * 1024 + k0 + aL_c * 4, &sm.s.A[buf][rowbase * 32]);
        }
#pragma unroll
        for (int i = 0; i < 4; i++) {
            int nbase = wave * 64 + i * 16;
            int n = nbase + bL_r;
            gload16(Wt + (size_t)n * 1024 + k0 + bL_c * 8, &sm.s.B[buf][nbase * 32]);
        }
    };

    // prologue: fill both buffers; wait only for tile 0 (8 newest stay in flight)
    stageAB(0, 0);
    stageAB(1, BK);
    asm volatile("s_waitcnt vmcnt(8)" ::: "memory");
    wg_barrier();

    int cur = 0;
    for (int t = 0; t < NKT; t++) {
        bf16x8 af[4], bfr[8];
#pragma unroll
        for (int mi = 0; mi < 4; mi++) {
            int row = wm + mi * 16 + mrow;
            f32x4 lo = *(const f32x4*)&sm.s.A[cur][row * 32 + (((quad * 2 + 0) ^ (mrow & 7)) * 4)];
            f32x4 hi = *(const f32x4*)&sm.s.A[cur][row * 32 + (((quad * 2 + 1) ^ (mrow & 7)) * 4)];
            af[mi] = cvt8(lo, hi);
        }
#pragma unroll
        for (int ni = 0; ni < 8; ni++) {
            int n = wn + ni * 16 + mrow;
            bfr[ni] = *(const bf16x8*)&sm.s.B[cur][n * 32 + ((quad ^ ((mrow >> 1) & 3)) * 8)];
        }
#pragma unroll
        for (int mi = 0; mi < 4; mi++)
#pragma unroll
            for (int ni = 0; ni < 8; ni++)
                acc[mi][ni] = __builtin_amdgcn_mfma_f32_16x16x32_bf16(af[mi], bfr[ni], acc[mi][ni], 0, 0, 0);

        wg_barrier();  // all waves done reading buf[cur]

        if (t + 2 < NKT) {
            stageAB(cur, (t + 2) * BK);                      // 8 new loads
            asm volatile("s_waitcnt vmcnt(8)" ::: "memory"); // oldest 8 = tile t+1 landed
        } else {
            asm volatile("s_waitcnt vmcnt(0)" ::: "memory"); // drain remaining
        }
        wg_barrier();  // buf[cur^1] fully resident
        cur ^= 1;
    }

    // epilogue: acc -> C LDS (scaled, bf16), then coalesced 16B/lane stores.
#pragma unroll
    for (int mi = 0; mi < 4; mi++) {
#pragma unroll
        for (int reg = 0; reg < 4; reg++) {
            int row = wm + mi * 16 + quad * 4 + reg;
            float nsv = ns_lds[row];
#pragma unroll
            for (int ni = 0; ni < 8; ni++) {
                int col = wn + ni * 16 + mrow;
                sm.C[row * CSTR + col] = f2bf(acc[mi][ni][reg] * nsv);
            }
        }
    }
    __syncthreads();
#pragma unroll
    for (int j = 0; j < 16; j++) {
        int row = wave * 2 + (lane >> 5) + j * 8;  // 8 rows/pass x 16 passes = 128
        int chunk = lane & 31;                     // 32 chunks x 8 shorts = 256 cols
        if (bm + row < M) {
            int4 v = *(const int4*)&sm.C[row * CSTR + chunk * 8];
            *(int4*)(hb + (size_t)(bm + row) * 256 + chunk * 8) = v;
        }
    }
}

// ---------- agg1 fused with layer-2 projection ----------
__global__ __launch_bounds__(256) void agg1_kernel(const short* __restrict__ hb,
                                                   const int* __restrict__ bucket,
                                                   const int* __restrict__ offsets,
                                                   const float* __restrict__ norm_dst,
                                                   const float* __restrict__ norm_src,
                                                   const float* __restrict__ b1,
                                                   const float* __restrict__ W2,
                                                   float* __restrict__ z, int N) {
    int wave = threadIdx.x >> 6;
    int lane = threadIdx.x & 63;
    int half = lane >> 5;       // which edge of the pair
    int col8 = lane & 31;       // 8-col group within 256
    int node = blockIdx.x * 4 + wave;
    if (node >= N) return;
    int beg = offsets[node], end = offsets[node + 1];
    float a[8] = {0.f, 0.f, 0.f, 0.f, 0.f, 0.f, 0.f, 0.f};
    int e = beg;
    for (; e + 16 <= end; e += 16) {  // 16 edges: 8 gathers of 16B in flight/lane
        bf16x8 v[8];
#pragma unroll
        for (int i = 0; i < 8; i++) {
            int s = bucket[e + 2 * i + half];
            v[i] = *(const bf16x8*)(hb + (size_t)s * 256 + col8 * 8);
        }
#pragma unroll
        for (int i = 0; i < 8; i++)
#pragma unroll
            for (int j = 0; j < 8; j++) a[j] += bf2f(v[i][j]);
    }
    for (; e + 8 <= end; e += 8) {
        bf16x8 v[4];
#pragma unroll
        for (int i = 0; i < 4; i++) {
            int s = bucket[e + 2 * i + half];
            v[i] = *(const bf16x8*)(hb + (size_t)s * 256 + col8 * 8);
        }
#pragma unroll
        for (int i = 0; i < 4; i++)
#pragma unroll
            for (int j = 0; j < 8; j++) a[j] += bf2f(v[i][j]);
    }
    for (; e + 2 <= end; e += 2) {
        int s0 = bucket[e + half];
        bf16x8 v0 = *(const bf16x8*)(hb + (size_t)s0 * 256 + col8 * 8);
#pragma unroll
        for (int j = 0; j < 8; j++) a[j] += bf2f(v0[j]);
    }
    if (e < end && half == 0) {
        int s0 = bucket[e];
        bf16x8 v0 = *(const bf16x8*)(hb + (size_t)s0 * 256 + col8 * 8);
#pragma unroll
        for (int j = 0; j < 8; j++) a[j] += bf2f(v0[j]);
    }
#pragma unroll
    for (int j = 0; j < 8; j++) a[j] += __shfl_xor(a[j], 32, 64);

    float nd = norm_dst[node];
    float4 b_lo = *(const float4*)(b1 + col8 * 8);
    float4 b_hi = *(const float4*)(b1 + col8 * 8 + 4);
    float4 w_lo = *(const float4*)(W2 + col8 * 8);
    float4 w_hi = *(const float4*)(W2 + col8 * 8 + 4);
    float p = 0.f;
    p += fmaxf(a[0] * nd + b_lo.x, 0.f) * w_lo.x;
    p += fmaxf(a[1] * nd + b_lo.y, 0.f) * w_lo.y;
    p += fmaxf(a[2] * nd + b_lo.z, 0.f) * w_lo.z;
    p += fmaxf(a[3] * nd + b_lo.w, 0.f) * w_lo.w;
    p += fmaxf(a[4] * nd + b_hi.x, 0.f) * w_hi.x;
    p += fmaxf(a[5] * nd + b_hi.y, 0.f) * w_hi.y;
    p += fmaxf(a[6] * nd + b_hi.z, 0.f) * w_hi.z;
    p += fmaxf(a[7] * nd + b_hi.w, 0.f) * w_hi.w;
#pragma unroll
    for (int off = 16; off > 0; off >>= 1) p += __shfl_xor(p, off, 64);
    if (lane == 0) z[node] = p * norm_src[node];
}

// ---------- agg2: out = relu(norm_dst * sum z[src] + b2) ----------
__global__ void agg2_kernel(const float* __restrict__ z, const int* __restrict__ bucket,
                            const int* __restrict__ offsets, const float* __restrict__ norm_dst,
                            const float* __restrict__ b2, float* __restrict__ out, int N) {
    int i = blockIdx.x * blockDim.x + threadIdx.x;
    if (i >= N) return;
    int beg = offsets[i], end = offsets[i + 1];
    float s = 0.f;
    for (int e = beg; e < end; e++) s += z[bucket[e]];
    out[i] = fmaxf(s * norm_dst[i] + b2[0], 0.f);
}

extern "C" void kernel_launch(void* const* d_in, const int* in_sizes, int n_in,
                              void* d_out, int out_size, void* d_ws, size_t ws_size,
                              hipStream_t stream) {
    const int D_HID = in_sizes[4];           // 256
    const int D_IN  = in_sizes[3] / D_HID;   // 1024
    const int N     = in_sizes[0] / D_IN;    // 50000
    const int E     = in_sizes[1];           // 800000

    const float* x   = (const float*)d_in[0];
    const int*   src = (const int*)d_in[1];
    const int*   dst = (const int*)d_in[2];
    const float* W1  = (const float*)d_in[3];
    const float* b1  = (const float*)d_in[4];
    const float* W2  = (const float*)d_in[5];
    const float* b2  = (const float*)d_in[6];
    float* out = (float*)d_out;

    char* p = (char*)d_ws;
    auto alloc = [&](size_t bytes) {
        void* r = (void*)p;
        p += (bytes + 255) & ~(size_t)255;
        return r;
    };
    const int NB = (N + 255) / 256;  // 196 scan blocks
    // deg_out | deg_in | status are contiguous -> one memset covers all three
    int*      deg_out  = (int*)alloc((size_t)N * 4);
    int*      deg_in   = (int*)alloc((size_t)N * 4);
    unsigned* status   = (unsigned*)alloc((size_t)NB * 4);
    float*    norm_src = (float*)alloc((size_t)N * 4);
    float*    norm_dst = (float*)alloc((size_t)N * 4);
    int*      offsets  = (int*)alloc((size_t)(N + 1) * 4);
    int*      rank     = (int*)alloc((size_t)E * 4);
    int*      bucket   = (int*)alloc((size_t)E * 4);
    short*    Wt       = (short*)alloc((size_t)D_IN * D_HID * 2);
    short*    hb       = (short*)alloc((size_t)N * D_HID * 2);
    float*    z        = (float*)alloc((size_t)N * 4);

    const int GB = (N + BM - 1) / BM;  // 391 gemm blocks

    size_t degpad = ((size_t)N * 4 + 255) & ~(size_t)255;
    hipMemsetAsync(deg_out, 0, degpad * 2 + (size_t)NB * 4, stream);

    deg_tr_kernel<<<256 + (E + 255) / 256, 256, 0, stream>>>(W1, Wt, src, dst, deg_out, deg_in, rank, E);
    scan_fused<<<NB, 256, 0, stream>>>(deg_in, deg_out, status, offsets, norm_src, norm_dst, N, E);
    gemm_scatter_kernel<<<GB + SCB, 256, 0, stream>>>(x, Wt, norm_src, hb, N,
                                                      src, dst, offsets, rank, bucket, E, GB);
    agg1_kernel<<<(N + 3) / 4, 256, 0, stream>>>(hb, bucket, offsets, norm_dst, norm_src, b1, W2, z, N);
    agg2_kernel<<<(N + 255) / 256, 256, 0, stream>>>(z, bucket, offsets, norm_dst, b2, out, N);
}